// Round 1
// baseline (462.170 us; speedup 1.0000x reference)
//
#include <hip/hip_runtime.h>

// GCN 2-layer forward on MI355X.
// Layout of d_ws (floats):
//   deg  [0, N)            in-degree incl. self-loop
//   dinv [N, 2N)           rsqrt(deg)
//   h1   [2N, 2N+64N)      X@W1 ; later reused as h2 (N*16)
//   x1   [2N+64N, 2N+128N) aggregated layer-1 activations

constexpr int N_NODES   = 100000;
constexpr int N_EDGES   = 1000000;
constexpr int D_FEAT    = 64;
constexpr int N_FILTER  = 64;
constexpr int N_CLASSES = 16;

__global__ void k_init_deg(float* __restrict__ deg) {
    int i = blockIdx.x * 256 + threadIdx.x;
    if (i < N_NODES) deg[i] = 1.0f;  // self-loop
}

__global__ void k_count_deg(const int* __restrict__ dst, float* __restrict__ deg) {
    int e = blockIdx.x * 256 + threadIdx.x;
    if (e < N_EDGES) atomicAdd(&deg[dst[e]], 1.0f);
}

// h1 = X @ W1; x1 = h1 * (1/deg) (self-loop term); dinv = rsqrt(deg)
// 4 rows per 256-thread block; W1 (16 KB) staged in LDS.
__global__ void k_gemm1(const float* __restrict__ X, const float* __restrict__ W1,
                        const float* __restrict__ deg, float* __restrict__ h1,
                        float* __restrict__ x1, float* __restrict__ dinv) {
    __shared__ float sW[64 * 64];
    __shared__ float sX[256];
    int t = threadIdx.x;
#pragma unroll
    for (int j = 0; j < 16; ++j) sW[t + 256 * j] = W1[t + 256 * j];
    int base = blockIdx.x * 256;           // 4 rows * 64 feats, contiguous
    sX[t] = X[base + t];
    __syncthreads();
    int r = t >> 6, c = t & 63;            // r uniform within a wave -> sX broadcast reads
    int row = blockIdx.x * 4 + r;
    float acc = 0.f;
#pragma unroll
    for (int k = 0; k < 64; ++k) acc += sX[r * 64 + k] * sW[k * 64 + c];
    float dg = deg[row];
    h1[row * 64 + c] = acc;
    x1[row * 64 + c] = acc / dg;           // dinv^2 == 1/deg
    if (c == 0) dinv[row] = rsqrtf(dg);
}

// One wave per edge, lane = feature. x1[dst] += h1[src] * dinv[s]*dinv[d]
__global__ void k_scatter1(const int* __restrict__ src, const int* __restrict__ dst,
                           const float* __restrict__ dinv, const float* __restrict__ h1,
                           float* __restrict__ x1) {
    int t = threadIdx.x;
    int e = blockIdx.x * 4 + (t >> 6);     // grid sized exactly: E/4 blocks
    int lane = t & 63;
    int s = src[e], d = dst[e];
    float norm = dinv[s] * dinv[d];
    atomicAdd(&x1[d * 64 + lane], h1[s * 64 + lane] * norm);
}

// h2 = relu(x1 + b1) @ W2 ; out = h2 * dinv^2 + b2 (self-loop init)
// 16 rows per 256-thread block; x1 tile padded to stride 65 to kill the
// 4-way bank conflict from r*64+k reads (r = lane>>4 spans 4 rows per wave).
__global__ void k_gemm2(const float* __restrict__ x1, const float* __restrict__ b1,
                        const float* __restrict__ W2, const float* __restrict__ b2,
                        const float* __restrict__ dinv, float* __restrict__ h2,
                        float* __restrict__ out) {
    __shared__ float sW[64 * 16];
    __shared__ float sX[16 * 65];
    __shared__ float sB1[64];
    int t = threadIdx.x;
#pragma unroll
    for (int j = 0; j < 4; ++j) sW[t + 256 * j] = W2[t + 256 * j];
    if (t < 64) sB1[t] = b1[t];
    __syncthreads();
    int base = blockIdx.x * (16 * 64);
#pragma unroll
    for (int j = 0; j < 4; ++j) {
        int idx = t + 256 * j;
        float v = x1[base + idx] + sB1[idx & 63];
        sX[(idx >> 6) * 65 + (idx & 63)] = fmaxf(v, 0.f);
    }
    __syncthreads();
    int r = t >> 4, c = t & 15;
    float acc = 0.f;
#pragma unroll
    for (int k = 0; k < 64; ++k) acc += sX[r * 65 + k] * sW[k * 16 + c];
    int row = blockIdx.x * 16 + r;
    float dv = dinv[row];
    h2[row * 16 + c] = acc;
    out[row * 16 + c] = acc * dv * dv + b2[c];
}

// 16 threads per edge. out[dst] += h2[src] * dinv[s]*dinv[d]
__global__ void k_scatter2(const int* __restrict__ src, const int* __restrict__ dst,
                           const float* __restrict__ dinv, const float* __restrict__ h2,
                           float* __restrict__ out) {
    int g = blockIdx.x * 256 + threadIdx.x;  // grid sized exactly: E*16 threads
    int e = g >> 4, f = g & 15;
    int s = src[e], d = dst[e];
    float norm = dinv[s] * dinv[d];
    atomicAdd(&out[d * 16 + f], h2[s * 16 + f] * norm);
}

extern "C" void kernel_launch(void* const* d_in, const int* in_sizes, int n_in,
                              void* d_out, int out_size, void* d_ws, size_t ws_size,
                              hipStream_t stream) {
    const float* X  = (const float*)d_in[0];
    const int*   ei = (const int*)d_in[1];   // [2, E] int32
    const float* W1 = (const float*)d_in[2];
    const float* b1 = (const float*)d_in[3];
    const float* W2 = (const float*)d_in[4];
    const float* b2 = (const float*)d_in[5];
    float* out = (float*)d_out;

    float* ws   = (float*)d_ws;
    float* deg  = ws;
    float* dinv = ws + N_NODES;
    float* h1   = ws + 2 * N_NODES;
    float* x1   = h1 + (size_t)N_NODES * 64;
    float* h2   = h1;  // h1 dead after scatter1; reuse for h2 (N*16 <= N*64)

    const int* src = ei;
    const int* dst = ei + N_EDGES;

    k_init_deg<<<(N_NODES + 255) / 256, 256, 0, stream>>>(deg);
    k_count_deg<<<(N_EDGES + 255) / 256, 256, 0, stream>>>(dst, deg);
    k_gemm1<<<N_NODES / 4, 256, 0, stream>>>(X, W1, deg, h1, x1, dinv);
    k_scatter1<<<N_EDGES / 4, 256, 0, stream>>>(src, dst, dinv, h1, x1);
    k_gemm2<<<N_NODES / 16, 256, 0, stream>>>(x1, b1, W2, b2, dinv, h2, out);
    k_scatter2<<<N_EDGES * 16 / 256, 256, 0, stream>>>(src, dst, dinv, h2, out);
}

// Round 3
// 319.976 us; speedup vs baseline: 1.4444x; 1.4444x over previous
//
#include <hip/hip_runtime.h>

// GCN 2-layer forward, CSR-gather formulation (no feature atomics).
//
// Math: deg[i] = 1 + indeg(i); dinv = rsqrt(deg)
//   h1s = (X@W1) * dinv[row]
//   y1[d] = relu(dinv[d]*(h1s[d] + sum_{s->d} h1s[s]) + b1)
//   h2s = (y1@W2) * dinv[row]        (fused into k_layer12, y1 never stored)
//   out[d] = dinv[d]*(h2s[d] + sum_{s->d} h2s[s]) + b2
//
// ws layout (ints then floats), ~37.2 MB total:
//   counts/cursor int[N] | row_ptr int[N+1] | blockSums int[256] | csr_src int[E]
//   dinv f[N] | h1s f[64N] | h2s f[16N]

constexpr int N = 100000;
constexpr int E = 1000000;
constexpr int SCAN_BLOCKS = (N + 1023) / 1024;  // 98

__device__ __forceinline__ float rl_f(float v, int lane) {
    return __int_as_float(__builtin_amdgcn_readlane(__float_as_int(v), lane));
}
__device__ __forceinline__ int rl_i(int v, int lane) {
    return __builtin_amdgcn_readlane(v, lane);
}

__global__ void k_hist(const int* __restrict__ dst, int* __restrict__ counts) {
    int e = blockIdx.x * 256 + threadIdx.x;
    if (e < E) atomicAdd(&counts[dst[e]], 1);
}

// per-block (1024-elem) sums of counts
__global__ void k_scan1(const int* __restrict__ counts, int* __restrict__ blockSums) {
    __shared__ int sd[256];
    int t = threadIdx.x;
    int base = blockIdx.x * 1024 + t * 4;
    int s = 0;
#pragma unroll
    for (int j = 0; j < 4; ++j) s += (base + j < N) ? counts[base + j] : 0;
    sd[t] = s;
    __syncthreads();
    for (int off = 128; off > 0; off >>= 1) {
        if (t < off) sd[t] += sd[t + off];
        __syncthreads();
    }
    if (t == 0) blockSums[blockIdx.x] = sd[0];
}

// serial exclusive scan of the 98 block sums (tiny)
__global__ void k_scan2(int* __restrict__ blockSums, int* __restrict__ row_ptr) {
    if (threadIdx.x == 0) {
        int run = 0;
        for (int i = 0; i < SCAN_BLOCKS; ++i) {
            int v = blockSums[i];
            blockSums[i] = run;
            run += v;
        }
        row_ptr[N] = run;  // == E
    }
}

// row_ptr / cursor / dinv.  counts_cursor is read (counts) then overwritten
// (cursor) through the SAME non-restrict pointer — no aliasing UB.
__global__ void k_scan3(int* counts_cursor, const int* __restrict__ blockSums,
                        int* __restrict__ row_ptr, float* __restrict__ dinv) {
    __shared__ int sd[256];
    int t = threadIdx.x;
    int base = blockIdx.x * 1024 + t * 4;
    int c[4];
    int s = 0;
#pragma unroll
    for (int j = 0; j < 4; ++j) {
        c[j] = (base + j < N) ? counts_cursor[base + j] : 0;
        s += c[j];
    }
    sd[t] = s;
    __syncthreads();
    // Hillis-Steele inclusive scan over 256 thread-sums
    for (int off = 1; off < 256; off <<= 1) {
        int x = (t >= off) ? sd[t - off] : 0;
        __syncthreads();
        sd[t] += x;
        __syncthreads();
    }
    int run = sd[t] - s + blockSums[blockIdx.x];  // exclusive prefix for this thread
#pragma unroll
    for (int j = 0; j < 4; ++j) {
        int i = base + j;
        if (i < N) {
            row_ptr[i] = run;
            counts_cursor[i] = run;  // cursor init
            dinv[i] = rsqrtf((float)(c[j] + 1));
            run += c[j];
        }
    }
}

__global__ void k_fill(const int* __restrict__ src, const int* __restrict__ dst,
                       int* __restrict__ cursor, int* __restrict__ csr_src) {
    int e = blockIdx.x * 256 + threadIdx.x;
    if (e < E) {
        int pos = atomicAdd(&cursor[dst[e]], 1);
        csr_src[pos] = src[e];
    }
}

// h1s[row][c] = (X[row] . W1[:,c]) * dinv[row].  W1 column in 64 VGPRs/lane,
// X row broadcast via v_readlane — no LDS.
__global__ void k_gemm1(const float* __restrict__ X, const float* __restrict__ W1,
                        const float* __restrict__ dinv, float* __restrict__ h1s) {
    int t = threadIdx.x;
    int lane = t & 63;
    int wid = (blockIdx.x * 256 + t) >> 6;  // 4096 waves
    float w1[64];
#pragma unroll
    for (int k = 0; k < 64; ++k) w1[k] = W1[k * 64 + lane];
    for (int row = wid; row < N; row += 4096) {
        float x = X[(size_t)row * 64 + lane];
        float acc = 0.f;
#pragma unroll
        for (int k = 0; k < 64; ++k) acc = fmaf(rl_f(x, k), w1[k], acc);
        h1s[(size_t)row * 64 + lane] = acc * dinv[row];
    }
}

// Fused: gather layer-1 (CSR), +b1, relu, y1@W2, scale by dinv -> h2s[N,16].
// One wave per node.  All cross-lane ops (readlane / shfl) execute only in
// wave-uniform control flow (base-loop bounds are uniform; readlane ignores
// exec anyway).
__global__ void k_layer12(const int* __restrict__ row_ptr, const int* __restrict__ csr_src,
                          const float* __restrict__ dinv, const float* __restrict__ h1s,
                          const float* __restrict__ b1, const float* __restrict__ W2,
                          float* __restrict__ h2s) {
    int t = threadIdx.x;
    int lane = t & 63;
    int g = lane >> 4, c = lane & 15;
    int wid = (blockIdx.x * 256 + t) >> 6;  // 8192 waves
    float w2[16];
#pragma unroll
    for (int j = 0; j < 16; ++j) w2[j] = W2[(g * 16 + j) * 16 + c];
    float b1v = b1[lane];

    for (int d = wid; d < N; d += 8192) {
        int rp0 = row_ptr[d], rp1 = row_ptr[d + 1];
        float dv = dinv[d];
        float a0 = h1s[(size_t)d * 64 + lane];  // self term
        float a1 = 0.f, a2 = 0.f, a3 = 0.f;
        for (int base = rp0; base < rp1; base += 64) {   // wave-uniform bounds
            int nloc = min(64, rp1 - base);
            int sidx = (lane < nloc) ? csr_src[base + lane] : 0;
            int j = 0;
            for (; j + 3 < nloc; j += 4) {               // uniform trip count
                int s0 = rl_i(sidx, j), s1 = rl_i(sidx, j + 1);
                int s2 = rl_i(sidx, j + 2), s3 = rl_i(sidx, j + 3);
                a0 += h1s[(size_t)s0 * 64 + lane];
                a1 += h1s[(size_t)s1 * 64 + lane];
                a2 += h1s[(size_t)s2 * 64 + lane];
                a3 += h1s[(size_t)s3 * 64 + lane];
            }
            for (; j < nloc; ++j) a0 += h1s[(size_t)rl_i(sidx, j) * 64 + lane];
        }
        float y = fmaxf(dv * ((a0 + a1) + (a2 + a3)) + b1v, 0.f);
        // h2[d][c] = sum_k y[k] * W2[k][c]; group g covers k = g*16..g*16+15
        float o = 0.f;
#pragma unroll
        for (int j = 0; j < 16; ++j) o = fmaf(__shfl(y, (lane & 48) | j), w2[j], o);
        o += __shfl_xor(o, 16);
        o += __shfl_xor(o, 32);
        if (lane < 16) h2s[(size_t)d * 16 + lane] = o * dv;
    }
}

// out[d] = dinv[d]*(h2s[d] + sum_in h2s[s]) + b2.  Wave per node; each 16-lane
// group takes every 4th edge and broadcast-loads csr_src directly — NO
// cross-lane ops inside the divergent loop (R2's bug: __shfl from exited
// lanes returned 0 for ~1% of nodes).
__global__ void k_gather2(const int* __restrict__ row_ptr, const int* __restrict__ csr_src,
                          const float* __restrict__ dinv, const float* __restrict__ h2s,
                          const float* __restrict__ b2, float* __restrict__ out) {
    int t = threadIdx.x;
    int lane = t & 63;
    int g = lane >> 4, c = lane & 15;
    int d = blockIdx.x * 4 + (t >> 6);  // exactly N/4 blocks
    int rp0 = row_ptr[d], rp1 = row_ptr[d + 1];
    float dv = dinv[d];
    float acc = (g == 0) ? h2s[(size_t)d * 16 + c] : 0.f;  // self term once
    for (int j = rp0 + g; j < rp1; j += 4) {
        int s = csr_src[j];                 // 16 lanes, same word -> 1 request
        acc += h2s[(size_t)s * 16 + c];
    }
    acc += __shfl_xor(acc, 16);             // after reconvergence: safe
    acc += __shfl_xor(acc, 32);
    if (lane < 16) out[(size_t)d * 16 + c] = dv * acc + b2[c];
}

extern "C" void kernel_launch(void* const* d_in, const int* in_sizes, int n_in,
                              void* d_out, int out_size, void* d_ws, size_t ws_size,
                              hipStream_t stream) {
    const float* X  = (const float*)d_in[0];
    const int*   ei = (const int*)d_in[1];  // [2, E] int32: src then dst
    const float* W1 = (const float*)d_in[2];
    const float* b1 = (const float*)d_in[3];
    const float* W2 = (const float*)d_in[4];
    const float* b2 = (const float*)d_in[5];
    float* out = (float*)d_out;

    int* counts    = (int*)d_ws;          // aliased as cursor after scan3
    int* row_ptr   = counts + N;
    int* blockSums = row_ptr + N + 1;
    int* csr_src   = blockSums + 256;
    float* dinv    = (float*)(csr_src + E);
    float* h1s     = dinv + N;
    float* h2s     = h1s + (size_t)N * 64;

    const int* src = ei;
    const int* dst = ei + E;

    hipMemsetAsync(counts, 0, N * sizeof(int), stream);
    k_hist<<<(E + 255) / 256, 256, 0, stream>>>(dst, counts);
    k_scan1<<<SCAN_BLOCKS, 256, 0, stream>>>(counts, blockSums);
    k_scan2<<<1, 64, 0, stream>>>(blockSums, row_ptr);
    k_scan3<<<SCAN_BLOCKS, 256, 0, stream>>>(counts, blockSums, row_ptr, dinv);
    k_fill<<<(E + 255) / 256, 256, 0, stream>>>(src, dst, counts, csr_src);
    k_gemm1<<<1024, 256, 0, stream>>>(X, W1, dinv, h1s);
    k_layer12<<<2048, 256, 0, stream>>>(row_ptr, csr_src, dinv, h1s, b1, W2, h2s);
    k_gather2<<<N / 4, 256, 0, stream>>>(row_ptr, csr_src, dinv, h2s, b2, out);
}

// Round 4
// 266.341 us; speedup vs baseline: 1.7353x; 1.2014x over previous
//
#include <hip/hip_runtime.h>
#include <hip/hip_bf16.h>

// GCN 2-layer forward — bucketed CSR build + bf16 intermediates.
//
// Math: deg[i] = 1 + indeg(i); dinv = rsqrt(deg)
//   h1s = (X@W1) * dinv[row]                       (bf16)
//   y1[d] = relu(dinv[d]*(h1s[d] + sum_in h1s[s]) + b1)
//   h2s = (y1@W2) * dinv[row]                      (bf16, fused in k_layer12)
//   out[d] = dinv[d]*(h2s[d] + sum_in h2s[s]) + b2 (fp32)
//
// CSR build: edges -> 196 fixed-cap dst-buckets (512 nodes each, 4B packed
// entries) -> per-bucket LDS counting sort. Kills R3's 69 MB write
// amplification (random 4B stores across 4 MB) by keeping active write
// regions to 196 line-groups.

constexpr int N = 100000;
constexpr int E = 1000000;
constexpr int NB = (N + 511) / 512;   // 196 buckets of 512 dst nodes
constexpr int CAP = 6144;             // mean fill 5120, sd ~71 -> 14 sigma
constexpr int CSTRIDE = 32;           // cursor padding: 1 per 128B line

__device__ __forceinline__ float rl_f(float v, int lane) {
    return __int_as_float(__builtin_amdgcn_readlane(__float_as_int(v), lane));
}
__device__ __forceinline__ int rl_i(int v, int lane) {
    return __builtin_amdgcn_readlane(v, lane);
}

// Scatter edges into coarse buckets. pack = (dst&511)<<17 | src  (src < 2^17).
__global__ void k_bfill(const int* __restrict__ src, const int* __restrict__ dst,
                        int* __restrict__ cursor, int* __restrict__ bkt) {
    int e = blockIdx.x * 256 + threadIdx.x;
    if (e >= E) return;
    int d = dst[e];
    int b = d >> 9;
    int pos = atomicAdd(&cursor[b * CSTRIDE], 1);
    if (pos < CAP) bkt[b * CAP + pos] = ((d & 511) << 17) | src[e];
}

// Exclusive scan of 196 bucket counts (single block); row_ptr[N] = E.
__global__ void k_bscan(const int* __restrict__ cursor, int* __restrict__ bucket_base,
                        int* __restrict__ row_ptr) {
    __shared__ int sd[256];
    int t = threadIdx.x;
    int c = (t < NB) ? cursor[t * CSTRIDE] : 0;
    sd[t] = c;
    __syncthreads();
    for (int off = 1; off < 256; off <<= 1) {
        int x = (t >= off) ? sd[t - off] : 0;
        __syncthreads();
        sd[t] += x;
        __syncthreads();
    }
    if (t < NB) bucket_base[t] = sd[t] - c;
    if (t == 0) row_ptr[N] = E;
}

// One workgroup per bucket: LDS histogram of 512 local nodes, LDS scan,
// write row_ptr/dinv, then place csr_src (20KB region -> L2-local).
__global__ void k_bfine(const int* __restrict__ cursor, const int* __restrict__ bucket_base,
                        const int* __restrict__ bkt, int* __restrict__ row_ptr,
                        float* __restrict__ dinv, int* __restrict__ csr_src) {
    __shared__ int cnt[512];
    __shared__ int excl[512];
    __shared__ int s2[256];
    int b = blockIdx.x;
    int t = threadIdx.x;
    int m = cursor[b * CSTRIDE];
    int base = bucket_base[b];
    const int* bb = bkt + b * CAP;
    cnt[t] = 0; cnt[t + 256] = 0;
    __syncthreads();
    for (int j = t; j < m; j += 256) atomicAdd(&cnt[bb[j] >> 17], 1);
    __syncthreads();
    int pairSum = cnt[2 * t] + cnt[2 * t + 1];
    s2[t] = pairSum;
    __syncthreads();
    for (int off = 1; off < 256; off <<= 1) {
        int x = (t >= off) ? s2[t - off] : 0;
        __syncthreads();
        s2[t] += x;
        __syncthreads();
    }
    int exclPair = s2[t] - pairSum;
    excl[2 * t] = exclPair;
    excl[2 * t + 1] = exclPair + cnt[2 * t];
    __syncthreads();
#pragma unroll
    for (int h = 0; h < 2; ++h) {
        int k = t + h * 256;
        int node = b * 512 + k;
        if (node < N) {
            row_ptr[node] = base + excl[k];
            dinv[node] = rsqrtf((float)(cnt[k] + 1));
        }
    }
    __syncthreads();
    for (int j = t; j < m; j += 256) {
        int v = bb[j];
        int p = atomicAdd(&excl[v >> 17], 1);   // excl doubles as cursor
        csr_src[base + p] = v & 0x1FFFF;
    }
}

// h1s[row][c] = (X[row] . W1[:,c]) * dinv[row], stored bf16.
// W1 column in 64 VGPRs/lane, X row broadcast via v_readlane — no LDS.
__global__ void k_gemm1(const float* __restrict__ X, const float* __restrict__ W1,
                        const float* __restrict__ dinv, __hip_bfloat16* __restrict__ h1s) {
    int t = threadIdx.x;
    int lane = t & 63;
    int wid = (blockIdx.x * 256 + t) >> 6;  // 4096 waves
    float w1[64];
#pragma unroll
    for (int k = 0; k < 64; ++k) w1[k] = W1[k * 64 + lane];
    for (int row = wid; row < N; row += 4096) {
        float x = X[(size_t)row * 64 + lane];
        float acc = 0.f;
#pragma unroll
        for (int k = 0; k < 64; ++k) acc = fmaf(rl_f(x, k), w1[k], acc);
        h1s[(size_t)row * 64 + lane] = __float2bfloat16(acc * dinv[row]);
    }
}

// Fused: gather layer-1 (CSR), +b1, relu, y1@W2, scale -> h2s (bf16).
// One wave per node; cross-lane ops only under wave-uniform control flow.
__global__ void k_layer12(const int* __restrict__ row_ptr, const int* __restrict__ csr_src,
                          const float* __restrict__ dinv, const __hip_bfloat16* __restrict__ h1s,
                          const float* __restrict__ b1, const float* __restrict__ W2,
                          __hip_bfloat16* __restrict__ h2s) {
    int t = threadIdx.x;
    int lane = t & 63;
    int g = lane >> 4, c = lane & 15;
    int wid = (blockIdx.x * 256 + t) >> 6;  // 8192 waves
    float w2[16];
#pragma unroll
    for (int j = 0; j < 16; ++j) w2[j] = W2[(g * 16 + j) * 16 + c];
    float b1v = b1[lane];

    for (int d = wid; d < N; d += 8192) {
        int rp0 = row_ptr[d], rp1 = row_ptr[d + 1];
        float dv = dinv[d];
        float a0 = __bfloat162float(h1s[(size_t)d * 64 + lane]);  // self term
        float a1 = 0.f, a2 = 0.f, a3 = 0.f;
        for (int base = rp0; base < rp1; base += 64) {   // wave-uniform bounds
            int nloc = min(64, rp1 - base);
            int sidx = (lane < nloc) ? csr_src[base + lane] : 0;
            int j = 0;
            for (; j + 3 < nloc; j += 4) {               // uniform trip count
                int s0 = rl_i(sidx, j), s1 = rl_i(sidx, j + 1);
                int s2v = rl_i(sidx, j + 2), s3 = rl_i(sidx, j + 3);
                a0 += __bfloat162float(h1s[(size_t)s0 * 64 + lane]);
                a1 += __bfloat162float(h1s[(size_t)s1 * 64 + lane]);
                a2 += __bfloat162float(h1s[(size_t)s2v * 64 + lane]);
                a3 += __bfloat162float(h1s[(size_t)s3 * 64 + lane]);
            }
            for (; j < nloc; ++j)
                a0 += __bfloat162float(h1s[(size_t)rl_i(sidx, j) * 64 + lane]);
        }
        float y = fmaxf(dv * ((a0 + a1) + (a2 + a3)) + b1v, 0.f);
        float o = 0.f;
#pragma unroll
        for (int j = 0; j < 16; ++j) o = fmaf(__shfl(y, (lane & 48) | j), w2[j], o);
        o += __shfl_xor(o, 16);
        o += __shfl_xor(o, 32);
        if (lane < 16) h2s[(size_t)d * 16 + lane] = __float2bfloat16(o * dv);
    }
}

// out[d] = dinv[d]*(h2s[d] + sum_in h2s[s]) + b2.  h2s is 3.2 MB -> L2-hot.
// No cross-lane ops inside the divergent loop.
__global__ void k_gather2(const int* __restrict__ row_ptr, const int* __restrict__ csr_src,
                          const float* __restrict__ dinv, const __hip_bfloat16* __restrict__ h2s,
                          const float* __restrict__ b2, float* __restrict__ out) {
    int t = threadIdx.x;
    int lane = t & 63;
    int g = lane >> 4, c = lane & 15;
    int d = blockIdx.x * 4 + (t >> 6);  // exactly N/4 blocks
    int rp0 = row_ptr[d], rp1 = row_ptr[d + 1];
    float dv = dinv[d];
    float acc = (g == 0) ? __bfloat162float(h2s[(size_t)d * 16 + c]) : 0.f;
    for (int j = rp0 + g; j < rp1; j += 4) {
        int s = csr_src[j];                 // 16 lanes same word -> 1 request
        acc += __bfloat162float(h2s[(size_t)s * 16 + c]);
    }
    acc += __shfl_xor(acc, 16);             // after reconvergence: safe
    acc += __shfl_xor(acc, 32);
    if (lane < 16) out[(size_t)d * 16 + c] = dv * acc + b2[c];
}

extern "C" void kernel_launch(void* const* d_in, const int* in_sizes, int n_in,
                              void* d_out, int out_size, void* d_ws, size_t ws_size,
                              hipStream_t stream) {
    const float* X  = (const float*)d_in[0];
    const int*   ei = (const int*)d_in[1];  // [2, E] int32: src then dst
    const float* W1 = (const float*)d_in[2];
    const float* b1 = (const float*)d_in[3];
    const float* W2 = (const float*)d_in[4];
    const float* b2 = (const float*)d_in[5];
    float* out = (float*)d_out;

    int* cursor      = (int*)d_ws;                 // NB*CSTRIDE ints (padded)
    int* bucket_base = cursor + NB * CSTRIDE;      // NB
    int* row_ptr     = bucket_base + NB;           // N+1
    int* bkt         = row_ptr + N + 1;            // NB*CAP
    int* csr_src     = bkt + NB * CAP;             // E
    float* dinv      = (float*)(csr_src + E);      // N
    __hip_bfloat16* h1s = (__hip_bfloat16*)(dinv + N);       // 64N
    __hip_bfloat16* h2s = h1s + (size_t)N * 64;              // 16N

    const int* src = ei;
    const int* dst = ei + E;

    hipMemsetAsync(cursor, 0, NB * CSTRIDE * sizeof(int), stream);
    k_bfill<<<(E + 255) / 256, 256, 0, stream>>>(src, dst, cursor, bkt);
    k_bscan<<<1, 256, 0, stream>>>(cursor, bucket_base, row_ptr);
    k_bfine<<<NB, 256, 0, stream>>>(cursor, bucket_base, bkt, row_ptr, dinv, csr_src);
    k_gemm1<<<1024, 256, 0, stream>>>(X, W1, dinv, h1s);
    k_layer12<<<2048, 256, 0, stream>>>(row_ptr, csr_src, dinv, h1s, b1, W2, h2s);
    k_gather2<<<N / 4, 256, 0, stream>>>(row_ptr, csr_src, dinv, h2s, b2, out);
}

// Round 5
// 219.415 us; speedup vs baseline: 2.1064x; 1.2139x over previous
//
#include <hip/hip_runtime.h>
#include <hip/hip_bf16.h>

// GCN 2-layer forward — LDS-binned bucketed CSR build + bf16 intermediates.
//
// Math: deg[i] = 1 + indeg(i); dinv = rsqrt(deg)
//   h1s = (X@W1) * dinv[row]                       (bf16)
//   y1[d] = relu(dinv[d]*(h1s[d] + sum_in h1s[s]) + b1)
//   h2s = (y1@W2) * dinv[row]                      (bf16, fused in k_layer12)
//   out[d] = dinv[d]*(h2s[d] + sum_in h2s[s]) + b2 (fp32)
//
// CSR build: k_bfill stages 2048 edges/block bucket-sorted in LDS and writes
// one contiguous run per (block,bucket) — R4's per-edge global atomic+4B
// random store caused 49 MB of cross-XCD line ping-pong (49 B/edge written).

constexpr int N = 100000;
constexpr int E = 1000000;
constexpr int NB = (N + 511) / 512;   // 196 buckets of 512 dst nodes
constexpr int CAP = 6144;             // mean fill 5102, sd ~71 -> 14 sigma
constexpr int CSTRIDE = 32;           // cursor padding: 1 per 128B line
constexpr int CHUNK = 2048;           // edges per k_bfill block
constexpr int NBLK = (E + CHUNK - 1) / CHUNK;  // 489

__device__ __forceinline__ float rl_f(float v, int lane) {
    return __int_as_float(__builtin_amdgcn_readlane(__float_as_int(v), lane));
}
__device__ __forceinline__ int rl_i(int v, int lane) {
    return __builtin_amdgcn_readlane(v, lane);
}

// Two-pass LDS-binned scatter into coarse buckets.
// pack = (dst&511)<<17 | src  (src < 2^17).
__global__ void k_bfill(const int* __restrict__ src, const int* __restrict__ dst,
                        int* __restrict__ cursor, int* __restrict__ bkt) {
    __shared__ int hist[256];            // per-bucket count (196 used)
    __shared__ int lbase[256];           // exclusive scan of hist
    __shared__ int gbase[256];           // global base reserved per bucket
    __shared__ int lcur[256];            // LDS placement cursor
    __shared__ int stage[CHUNK];         // bucket-sorted packed edges
    __shared__ unsigned char sbkt[CHUNK];// bucket id per staged slot
    int t = threadIdx.x;
    int e0 = blockIdx.x * CHUNK;
    int cnt = min(CHUNK, E - e0);

    hist[t] = 0;
    __syncthreads();
    for (int j = t; j < cnt; j += 256)
        atomicAdd(&hist[dst[e0 + j] >> 9], 1);
    __syncthreads();
    int h = hist[t];
    lbase[t] = h;
    __syncthreads();
    for (int off = 1; off < 256; off <<= 1) {   // Hillis-Steele inclusive
        int x = (t >= off) ? lbase[t - off] : 0;
        __syncthreads();
        lbase[t] += x;
        __syncthreads();
    }
    int excl = lbase[t] - h;
    __syncthreads();
    lbase[t] = excl;
    lcur[t] = 0;
    if (t < NB) gbase[t] = h ? atomicAdd(&cursor[t * CSTRIDE], h) : 0;
    __syncthreads();
    for (int j = t; j < cnt; j += 256) {        // stage bucket-sorted
        int d = dst[e0 + j];
        int b = d >> 9;
        int pos = lbase[b] + atomicAdd(&lcur[b], 1);
        stage[pos] = ((d & 511) << 17) | src[e0 + j];
        sbkt[pos] = (unsigned char)b;
    }
    __syncthreads();
    for (int j = t; j < cnt; j += 256) {        // contiguous-run copy out
        int b = sbkt[j];
        int gpos = gbase[b] + (j - lbase[b]);
        if (gpos < CAP) bkt[b * CAP + gpos] = stage[j];
    }
}

// Exclusive scan of 196 bucket counts (single block); row_ptr[N] = E.
__global__ void k_bscan(const int* __restrict__ cursor, int* __restrict__ bucket_base,
                        int* __restrict__ row_ptr) {
    __shared__ int sd[256];
    int t = threadIdx.x;
    int c = (t < NB) ? cursor[t * CSTRIDE] : 0;
    sd[t] = c;
    __syncthreads();
    for (int off = 1; off < 256; off <<= 1) {
        int x = (t >= off) ? sd[t - off] : 0;
        __syncthreads();
        sd[t] += x;
        __syncthreads();
    }
    if (t < NB) bucket_base[t] = sd[t] - c;
    if (t == 0) row_ptr[N] = E;
}

// One workgroup per bucket: LDS histogram of 512 local nodes, LDS scan,
// write row_ptr/dinv, then place csr_src (20KB region -> L2-local).
__global__ void k_bfine(const int* __restrict__ cursor, const int* __restrict__ bucket_base,
                        const int* __restrict__ bkt, int* __restrict__ row_ptr,
                        float* __restrict__ dinv, int* __restrict__ csr_src) {
    __shared__ int cnt[512];
    __shared__ int excl[512];
    __shared__ int s2[256];
    int b = blockIdx.x;
    int t = threadIdx.x;
    int m = cursor[b * CSTRIDE];
    int base = bucket_base[b];
    const int* bb = bkt + b * CAP;
    cnt[t] = 0; cnt[t + 256] = 0;
    __syncthreads();
    for (int j = t; j < m; j += 256) atomicAdd(&cnt[bb[j] >> 17], 1);
    __syncthreads();
    int pairSum = cnt[2 * t] + cnt[2 * t + 1];
    s2[t] = pairSum;
    __syncthreads();
    for (int off = 1; off < 256; off <<= 1) {
        int x = (t >= off) ? s2[t - off] : 0;
        __syncthreads();
        s2[t] += x;
        __syncthreads();
    }
    int exclPair = s2[t] - pairSum;
    excl[2 * t] = exclPair;
    excl[2 * t + 1] = exclPair + cnt[2 * t];
    __syncthreads();
#pragma unroll
    for (int hh = 0; hh < 2; ++hh) {
        int k = t + hh * 256;
        int node = b * 512 + k;
        if (node < N) {
            row_ptr[node] = base + excl[k];
            dinv[node] = rsqrtf((float)(cnt[k] + 1));
        }
    }
    __syncthreads();
    for (int j = t; j < m; j += 256) {
        int v = bb[j];
        int p = atomicAdd(&excl[v >> 17], 1);   // excl doubles as cursor
        csr_src[base + p] = v & 0x1FFFF;
    }
}

// h1s[row][c] = (X[row] . W1[:,c]) * dinv[row], stored bf16.
// W1 column in 64 VGPRs/lane, X row broadcast via v_readlane — no LDS.
__global__ void k_gemm1(const float* __restrict__ X, const float* __restrict__ W1,
                        const float* __restrict__ dinv, __hip_bfloat16* __restrict__ h1s) {
    int t = threadIdx.x;
    int lane = t & 63;
    int wid = (blockIdx.x * 256 + t) >> 6;  // 4096 waves
    float w1[64];
#pragma unroll
    for (int k = 0; k < 64; ++k) w1[k] = W1[k * 64 + lane];
    for (int row = wid; row < N; row += 4096) {
        float x = X[(size_t)row * 64 + lane];
        float acc = 0.f;
#pragma unroll
        for (int k = 0; k < 64; ++k) acc = fmaf(rl_f(x, k), w1[k], acc);
        h1s[(size_t)row * 64 + lane] = __float2bfloat16(acc * dinv[row]);
    }
}

// Fused: gather layer-1 (CSR), +b1, relu, y1@W2, scale -> h2s (bf16).
// One wave per node; cross-lane ops only under wave-uniform control flow.
__global__ void k_layer12(const int* __restrict__ row_ptr, const int* __restrict__ csr_src,
                          const float* __restrict__ dinv, const __hip_bfloat16* __restrict__ h1s,
                          const float* __restrict__ b1, const float* __restrict__ W2,
                          __hip_bfloat16* __restrict__ h2s) {
    int t = threadIdx.x;
    int lane = t & 63;
    int g = lane >> 4, c = lane & 15;
    int wid = (blockIdx.x * 256 + t) >> 6;  // 8192 waves
    float w2[16];
#pragma unroll
    for (int j = 0; j < 16; ++j) w2[j] = W2[(g * 16 + j) * 16 + c];
    float b1v = b1[lane];

    for (int d = wid; d < N; d += 8192) {
        int rp0 = row_ptr[d], rp1 = row_ptr[d + 1];
        float dv = dinv[d];
        float a0 = __bfloat162float(h1s[(size_t)d * 64 + lane]);  // self term
        float a1 = 0.f, a2 = 0.f, a3 = 0.f;
        for (int base = rp0; base < rp1; base += 64) {   // wave-uniform bounds
            int nloc = min(64, rp1 - base);
            int sidx = (lane < nloc) ? csr_src[base + lane] : 0;
            int j = 0;
            for (; j + 3 < nloc; j += 4) {               // uniform trip count
                int s0 = rl_i(sidx, j), s1 = rl_i(sidx, j + 1);
                int s2v = rl_i(sidx, j + 2), s3 = rl_i(sidx, j + 3);
                a0 += __bfloat162float(h1s[(size_t)s0 * 64 + lane]);
                a1 += __bfloat162float(h1s[(size_t)s1 * 64 + lane]);
                a2 += __bfloat162float(h1s[(size_t)s2v * 64 + lane]);
                a3 += __bfloat162float(h1s[(size_t)s3 * 64 + lane]);
            }
            for (; j < nloc; ++j)
                a0 += __bfloat162float(h1s[(size_t)rl_i(sidx, j) * 64 + lane]);
        }
        float y = fmaxf(dv * ((a0 + a1) + (a2 + a3)) + b1v, 0.f);
        float o = 0.f;
#pragma unroll
        for (int j = 0; j < 16; ++j) o = fmaf(__shfl(y, (lane & 48) | j), w2[j], o);
        o += __shfl_xor(o, 16);
        o += __shfl_xor(o, 32);
        if (lane < 16) h2s[(size_t)d * 16 + lane] = __float2bfloat16(o * dv);
    }
}

// out[d] = dinv[d]*(h2s[d] + sum_in h2s[s]) + b2.  h2s is 3.2 MB -> L2/L3-hot.
// No cross-lane ops inside the divergent loop.
__global__ void k_gather2(const int* __restrict__ row_ptr, const int* __restrict__ csr_src,
                          const float* __restrict__ dinv, const __hip_bfloat16* __restrict__ h2s,
                          const float* __restrict__ b2, float* __restrict__ out) {
    int t = threadIdx.x;
    int lane = t & 63;
    int g = lane >> 4, c = lane & 15;
    int d = blockIdx.x * 4 + (t >> 6);  // exactly N/4 blocks
    int rp0 = row_ptr[d], rp1 = row_ptr[d + 1];
    float dv = dinv[d];
    float acc = (g == 0) ? __bfloat162float(h2s[(size_t)d * 16 + c]) : 0.f;
    for (int j = rp0 + g; j < rp1; j += 4) {
        int s = csr_src[j];                 // 16 lanes same word -> 1 request
        acc += __bfloat162float(h2s[(size_t)s * 16 + c]);
    }
    acc += __shfl_xor(acc, 16);             // after reconvergence: safe
    acc += __shfl_xor(acc, 32);
    if (lane < 16) out[(size_t)d * 16 + c] = dv * acc + b2[c];
}

extern "C" void kernel_launch(void* const* d_in, const int* in_sizes, int n_in,
                              void* d_out, int out_size, void* d_ws, size_t ws_size,
                              hipStream_t stream) {
    const float* X  = (const float*)d_in[0];
    const int*   ei = (const int*)d_in[1];  // [2, E] int32: src then dst
    const float* W1 = (const float*)d_in[2];
    const float* b1 = (const float*)d_in[3];
    const float* W2 = (const float*)d_in[4];
    const float* b2 = (const float*)d_in[5];
    float* out = (float*)d_out;

    int* cursor      = (int*)d_ws;                 // NB*CSTRIDE ints (padded)
    int* bucket_base = cursor + NB * CSTRIDE;      // NB
    int* row_ptr     = bucket_base + NB;           // N+1
    int* bkt         = row_ptr + N + 1;            // NB*CAP
    int* csr_src     = bkt + NB * CAP;             // E
    float* dinv      = (float*)(csr_src + E);      // N
    __hip_bfloat16* h1s = (__hip_bfloat16*)(dinv + N);       // 64N
    __hip_bfloat16* h2s = h1s + (size_t)N * 64;              // 16N

    const int* src = ei;
    const int* dst = ei + E;

    hipMemsetAsync(cursor, 0, NB * CSTRIDE * sizeof(int), stream);
    k_bfill<<<NBLK, 256, 0, stream>>>(src, dst, cursor, bkt);
    k_bscan<<<1, 256, 0, stream>>>(cursor, bucket_base, row_ptr);
    k_bfine<<<NB, 256, 0, stream>>>(cursor, bucket_base, bkt, row_ptr, dinv, csr_src);
    k_gemm1<<<1024, 256, 0, stream>>>(X, W1, dinv, h1s);
    k_layer12<<<2048, 256, 0, stream>>>(row_ptr, csr_src, dinv, h1s, b1, W2, h2s);
    k_gather2<<<N / 4, 256, 0, stream>>>(row_ptr, csr_src, dinv, h2s, b2, out);
}

// Round 6
// 217.238 us; speedup vs baseline: 2.1275x; 1.0100x over previous
//
#include <hip/hip_runtime.h>
#include <hip/hip_bf16.h>

// GCN 2-layer forward — LDS-binned bucketed CSR build + bf16 intermediates,
// vectorized (uint2 / dword) gathers.
//
// Math: deg[i] = 1 + indeg(i); dinv = rsqrt(deg)
//   h1s = (X@W1) * dinv[row]                       (bf16)
//   y1[d] = relu(dinv[d]*(h1s[d] + sum_in h1s[s]) + b1)
//   h2s = (y1@W2) * dinv[row]                      (bf16, fused in k_layer12)
//   out[d] = dinv[d]*(h2s[d] + sum_in h2s[s]) + b2 (fp32)

constexpr int N = 100000;
constexpr int E = 1000000;
constexpr int NB = (N + 511) / 512;   // 196 buckets of 512 dst nodes
constexpr int CAP = 6144;             // mean fill 5102, sd ~71 -> 14 sigma
constexpr int CSTRIDE = 32;           // cursor padding: 1 per 128B line
constexpr int CHUNK = 2048;           // edges per k_bfill block
constexpr int NBLK = (E + CHUNK - 1) / CHUNK;  // 489

__device__ __forceinline__ float rl_f(float v, int l) {
    return __int_as_float(__builtin_amdgcn_readlane(__float_as_int(v), l));
}
__device__ __forceinline__ int rl_i(int v, int l) {
    return __builtin_amdgcn_readlane(v, l);
}
__device__ __forceinline__ float bflo(unsigned u) { return __uint_as_float(u << 16); }
__device__ __forceinline__ float bfhi(unsigned u) { return __uint_as_float(u & 0xffff0000u); }

// Two-pass LDS-binned scatter into coarse buckets.
// pack = (dst&511)<<17 | src  (src < 2^17).
__global__ void k_bfill(const int* __restrict__ src, const int* __restrict__ dst,
                        int* __restrict__ cursor, int* __restrict__ bkt) {
    __shared__ int hist[256];
    __shared__ int lbase[256];
    __shared__ int gbase[256];
    __shared__ int lcur[256];
    __shared__ int stage[CHUNK];
    __shared__ unsigned char sbkt[CHUNK];
    int t = threadIdx.x;
    int e0 = blockIdx.x * CHUNK;
    int cnt = min(CHUNK, E - e0);

    hist[t] = 0;
    __syncthreads();
    for (int j = t; j < cnt; j += 256)
        atomicAdd(&hist[dst[e0 + j] >> 9], 1);
    __syncthreads();
    int h = hist[t];
    lbase[t] = h;
    __syncthreads();
    for (int off = 1; off < 256; off <<= 1) {   // Hillis-Steele inclusive
        int x = (t >= off) ? lbase[t - off] : 0;
        __syncthreads();
        lbase[t] += x;
        __syncthreads();
    }
    int excl = lbase[t] - h;
    __syncthreads();
    lbase[t] = excl;
    lcur[t] = 0;
    if (t < NB) gbase[t] = h ? atomicAdd(&cursor[t * CSTRIDE], h) : 0;
    __syncthreads();
    for (int j = t; j < cnt; j += 256) {        // stage bucket-sorted
        int d = dst[e0 + j];
        int b = d >> 9;
        int pos = lbase[b] + atomicAdd(&lcur[b], 1);
        stage[pos] = ((d & 511) << 17) | src[e0 + j];
        sbkt[pos] = (unsigned char)b;
    }
    __syncthreads();
    for (int j = t; j < cnt; j += 256) {        // contiguous-run copy out
        int b = sbkt[j];
        int gpos = gbase[b] + (j - lbase[b]);
        if (gpos < CAP) bkt[b * CAP + gpos] = stage[j];
    }
}

// One workgroup per bucket. Fuses the old k_bscan: each block scans all 196
// bucket counts itself (196 L2-hot loads) to get its global base.
__global__ void k_bfine(const int* __restrict__ cursor, const int* __restrict__ bkt,
                        int* __restrict__ row_ptr, float* __restrict__ dinv,
                        int* __restrict__ csr_src) {
    __shared__ int sd[256];
    __shared__ int cnt[512];
    __shared__ int excl[512];
    __shared__ int s2[256];
    int b = blockIdx.x;
    int t = threadIdx.x;
    int c = (t < NB) ? cursor[t * CSTRIDE] : 0;
    sd[t] = c;
    __syncthreads();
    for (int off = 1; off < 256; off <<= 1) {
        int x = (t >= off) ? sd[t - off] : 0;
        __syncthreads();
        sd[t] += x;
        __syncthreads();
    }
    int m = cursor[b * CSTRIDE];
    int base = sd[b] - m;                       // exclusive prefix of bucket b
    if (b == 0 && t == 0) row_ptr[N] = E;
    const int* bb = bkt + b * CAP;
    cnt[t] = 0; cnt[t + 256] = 0;
    __syncthreads();
    for (int j = t; j < m; j += 256) atomicAdd(&cnt[bb[j] >> 17], 1);
    __syncthreads();
    int pairSum = cnt[2 * t] + cnt[2 * t + 1];
    s2[t] = pairSum;
    __syncthreads();
    for (int off = 1; off < 256; off <<= 1) {
        int x = (t >= off) ? s2[t - off] : 0;
        __syncthreads();
        s2[t] += x;
        __syncthreads();
    }
    int exclPair = s2[t] - pairSum;
    excl[2 * t] = exclPair;
    excl[2 * t + 1] = exclPair + cnt[2 * t];
    __syncthreads();
#pragma unroll
    for (int hh = 0; hh < 2; ++hh) {
        int k = t + hh * 256;
        int node = b * 512 + k;
        if (node < N) {
            row_ptr[node] = base + excl[k];
            dinv[node] = rsqrtf((float)(cnt[k] + 1));
        }
    }
    __syncthreads();
    for (int j = t; j < m; j += 256) {
        int v = bb[j];
        int p = atomicAdd(&excl[v >> 17], 1);   // excl doubles as cursor
        csr_src[base + p] = v & 0x1FFFF;
    }
}

// h1s[row][c] = (X[row] . W1[:,c]) * dinv[row], stored bf16 (packed stores).
__global__ void k_gemm1(const float* __restrict__ X, const float* __restrict__ W1,
                        const float* __restrict__ dinv, __hip_bfloat16* __restrict__ h1s) {
    int t = threadIdx.x;
    int lane = t & 63;
    int wid = (blockIdx.x * 256 + t) >> 6;  // 4096 waves
    float w1[64];
#pragma unroll
    for (int k = 0; k < 64; ++k) w1[k] = W1[k * 64 + lane];
    for (int row = wid; row < N; row += 4096) {
        float x = X[(size_t)row * 64 + lane];
        float acc = 0.f;
#pragma unroll
        for (int k = 0; k < 64; ++k) acc = fmaf(rl_f(x, k), w1[k], acc);
        acc *= dinv[row];
        float up = __shfl_xor(acc, 1);
        if (!(lane & 1)) {
            __hip_bfloat162 p;
            p.x = __float2bfloat16(acc);
            p.y = __float2bfloat16(up);
            *(__hip_bfloat162*)(h1s + (size_t)row * 64 + lane) = p;
        }
    }
}

// Fused: gather layer-1 (CSR), +b1, relu, y1@W2, scale -> h2s (bf16).
// One wave per node; 4 edges/step via quarter-groups, uint2 (bf16x4) loads.
// Cross-lane ops only under wave-uniform control flow.
__global__ void k_layer12(const int* __restrict__ row_ptr, const int* __restrict__ csr_src,
                          const float* __restrict__ dinv, const __hip_bfloat16* __restrict__ h1s,
                          const float* __restrict__ b1, const float* __restrict__ W2,
                          __hip_bfloat16* __restrict__ h2s) {
    int t = threadIdx.x;
    int lane = t & 63;
    int g = lane >> 4;        // quarter = which of 4 edges
    int q = lane & 15;        // col-quad: cols 4q..4q+3
    int wid = (blockIdx.x * 256 + t) >> 6;  // 8192 waves
    float w2[16];
#pragma unroll
    for (int j = 0; j < 16; ++j) w2[j] = W2[(g * 16 + j) * 16 + q];
    float b1v = b1[lane];
    const uint2* H = (const uint2*)h1s;     // row = 16 uint2

    for (int d = wid; d < N; d += 8192) {
        int rp0 = row_ptr[d], rp1 = row_ptr[d + 1];
        float dv = dinv[d];
        float a0 = 0.f, a1 = 0.f, a2 = 0.f, a3 = 0.f;
        if (g == 0) {                        // self term once
            uint2 u = H[(size_t)d * 16 + q];
            a0 = bflo(u.x); a1 = bfhi(u.x); a2 = bflo(u.y); a3 = bfhi(u.y);
        }
        for (int base = rp0; base < rp1; base += 64) {   // wave-uniform bounds
            int nloc = min(64, rp1 - base);
            int sidx = (lane < nloc) ? csr_src[base + lane] : 0;
            int j = 0;
            for (; j + 3 < nloc; j += 4) {               // uniform trip count
                int s0 = rl_i(sidx, j), s1 = rl_i(sidx, j + 1);
                int s2v = rl_i(sidx, j + 2), s3v = rl_i(sidx, j + 3);
                int sa = (lane & 16) ? s1 : s0;
                int sb = (lane & 16) ? s3v : s2v;
                int sg = (lane & 32) ? sb : sa;
                uint2 u = H[(size_t)sg * 16 + q];
                a0 += bflo(u.x); a1 += bfhi(u.x); a2 += bflo(u.y); a3 += bfhi(u.y);
            }
            for (; j < nloc; ++j) {                      // tail: quarter 0 only
                int s = rl_i(sidx, j);
                if (lane < 16) {
                    uint2 u = H[(size_t)s * 16 + q];
                    a0 += bflo(u.x); a1 += bfhi(u.x); a2 += bflo(u.y); a3 += bfhi(u.y);
                }
            }
        }
        // reduce across quarters
        a0 += __shfl_xor(a0, 16); a1 += __shfl_xor(a1, 16);
        a2 += __shfl_xor(a2, 16); a3 += __shfl_xor(a3, 16);
        a0 += __shfl_xor(a0, 32); a1 += __shfl_xor(a1, 32);
        a2 += __shfl_xor(a2, 32); a3 += __shfl_xor(a3, 32);
        // restore scalar layout: col `lane` = component (lane&3) of lane>>2
        int srcl = lane >> 2;
        float v0 = __shfl(a0, srcl), v1 = __shfl(a1, srcl);
        float v2 = __shfl(a2, srcl), v3 = __shfl(a3, srcl);
        float ysum = (lane & 2) ? ((lane & 1) ? v3 : v2) : ((lane & 1) ? v1 : v0);
        float y = fmaxf(fmaf(dv, ysum, b1v), 0.f);
        // h2[c] = sum_k y[k]*W2[k][c]; group g covers k = g*16..g*16+15
        float o = 0.f;
#pragma unroll
        for (int j = 0; j < 16; ++j) o = fmaf(__shfl(y, (lane & 48) | j), w2[j], o);
        o += __shfl_xor(o, 16);
        o += __shfl_xor(o, 32);
        o *= dv;
        float oup = __shfl_xor(o, 1);
        if (lane < 16 && !(lane & 1)) {
            __hip_bfloat162 p;
            p.x = __float2bfloat16(o);
            p.y = __float2bfloat16(oup);
            *(__hip_bfloat162*)(h2s + (size_t)d * 16 + lane) = p;
        }
    }
}

// out[d] = dinv[d]*(h2s[d] + sum_in h2s[s]) + b2.  8 edge-groups x dword loads.
// No cross-lane ops inside the divergent loop (shfl only after reconvergence).
__global__ void k_gather2(const int* __restrict__ row_ptr, const int* __restrict__ csr_src,
                          const float* __restrict__ dinv, const __hip_bfloat16* __restrict__ h2s,
                          const float* __restrict__ b2, float* __restrict__ out) {
    int t = threadIdx.x;
    int lane = t & 63;
    int g = lane >> 3;       // 8 edge-groups
    int cp = lane & 7;       // col-pair: cols 2cp, 2cp+1
    int d = blockIdx.x * 4 + (t >> 6);  // exactly N/4 blocks
    int rp0 = row_ptr[d], rp1 = row_ptr[d + 1];
    float dv = dinv[d];
    const unsigned* H2 = (const unsigned*)h2s;  // row = 8 dwords
    float e0 = 0.f, e1 = 0.f;
    if (g == 0) {
        unsigned u = H2[(size_t)d * 8 + cp];
        e0 = bflo(u); e1 = bfhi(u);
    }
    for (int j = rp0 + g; j < rp1; j += 8) {
        int s = csr_src[j];               // 8 lanes same word -> 1 request
        unsigned u = H2[(size_t)s * 8 + cp];
        e0 += bflo(u); e1 += bfhi(u);
    }
    e0 += __shfl_xor(e0, 8);  e1 += __shfl_xor(e1, 8);
    e0 += __shfl_xor(e0, 16); e1 += __shfl_xor(e1, 16);
    e0 += __shfl_xor(e0, 32); e1 += __shfl_xor(e1, 32);
    if (lane < 8) {
        float2 r;
        r.x = fmaf(dv, e0, b2[2 * cp]);
        r.y = fmaf(dv, e1, b2[2 * cp + 1]);
        *(float2*)(out + (size_t)d * 16 + 2 * cp) = r;
    }
}

extern "C" void kernel_launch(void* const* d_in, const int* in_sizes, int n_in,
                              void* d_out, int out_size, void* d_ws, size_t ws_size,
                              hipStream_t stream) {
    const float* X  = (const float*)d_in[0];
    const int*   ei = (const int*)d_in[1];  // [2, E] int32: src then dst
    const float* W1 = (const float*)d_in[2];
    const float* b1 = (const float*)d_in[3];
    const float* W2 = (const float*)d_in[4];
    const float* b2 = (const float*)d_in[5];
    float* out = (float*)d_out;

    int* cursor  = (int*)d_ws;                     // NB*CSTRIDE = 6272
    int* row_ptr = cursor + NB * CSTRIDE;          // N+4 (pad keeps h1s 16B-aligned)
    int* bkt     = row_ptr + N + 4;                // NB*CAP = 1204224
    int* csr_src = bkt + NB * CAP;                 // E
    float* dinv  = (float*)(csr_src + E);          // N
    __hip_bfloat16* h1s = (__hip_bfloat16*)(dinv + N);  // 64N  (16B-aligned)
    __hip_bfloat16* h2s = h1s + (size_t)N * 64;         // 16N

    const int* src = ei;
    const int* dst = ei + E;

    hipMemsetAsync(cursor, 0, NB * CSTRIDE * sizeof(int), stream);
    k_bfill<<<NBLK, 256, 0, stream>>>(src, dst, cursor, bkt);
    k_bfine<<<NB, 256, 0, stream>>>(cursor, bkt, row_ptr, dinv, csr_src);
    k_gemm1<<<1024, 256, 0, stream>>>(X, W1, dinv, h1s);
    k_layer12<<<2048, 256, 0, stream>>>(row_ptr, csr_src, dinv, h1s, b1, W2, h2s);
    k_gather2<<<N / 4, 256, 0, stream>>>(row_ptr, csr_src, dinv, h2s, b2, out);
}

// Round 7
// 213.860 us; speedup vs baseline: 2.1611x; 1.0158x over previous
//
#include <hip/hip_runtime.h>
#include <hip/hip_bf16.h>

// GCN 2-layer forward — bucketed CSR build + bf16 intermediates.
// R7: layer12/gather2 restructured for issue economy + MLP:
//   - uint4 (8-edge) / uint2 (16-edge) wide gathers
//   - ds_bpermute src-index broadcast (replaces readlane+cndmask chains)
//   - dummy zero row (index N) pads edge chunks: no tail predication
//   - 32-bit voffset addressing, contiguous node ranges per wave
//   - LDS y-transpose (stride-72 pad) replaces 48-instr xor reduce

constexpr int N = 100000;
constexpr int E = 1000000;
constexpr int NB = (N + 511) / 512;   // 196 buckets of 512 dst nodes
constexpr int CAP = 6144;             // mean fill 5102, sd ~71 -> 14 sigma
constexpr int CSTRIDE = 32;           // cursor padding: 1 per 128B line
constexpr int CHUNK = 4096;           // edges per k_bfill block
constexpr int NBLK = (E + CHUNK - 1) / CHUNK;  // 245
constexpr int NPW = 13;               // nodes per wave (layer12/gather2)
constexpr int NW = (N + NPW - 1) / NPW;        // 7693 waves
constexpr int NWBLK = (NW + 3) / 4;            // 1924 blocks

__device__ __forceinline__ float rl_f(float v, int l) {
    return __int_as_float(__builtin_amdgcn_readlane(__float_as_int(v), l));
}
__device__ __forceinline__ float bflo(unsigned u) { return __uint_as_float(u << 16); }
__device__ __forceinline__ float bfhi(unsigned u) { return __uint_as_float(u & 0xffff0000u); }

// Two-pass LDS-binned scatter into coarse buckets.
// pack = (dst&511)<<17 | src  (src < 2^17).
__global__ void k_bfill(const int* __restrict__ src, const int* __restrict__ dst,
                        int* __restrict__ cursor, int* __restrict__ bkt) {
    __shared__ int hist[256];
    __shared__ int lbase[256];
    __shared__ int gbase[256];
    __shared__ int lcur[256];
    __shared__ int stage[CHUNK];
    __shared__ unsigned char sbkt[CHUNK];
    int t = threadIdx.x;
    int e0 = blockIdx.x * CHUNK;
    int cnt = min(CHUNK, E - e0);

    hist[t] = 0;
    __syncthreads();
    for (int j = t; j < cnt; j += 256)
        atomicAdd(&hist[dst[e0 + j] >> 9], 1);
    __syncthreads();
    int h = hist[t];
    lbase[t] = h;
    __syncthreads();
    for (int off = 1; off < 256; off <<= 1) {   // Hillis-Steele inclusive
        int x = (t >= off) ? lbase[t - off] : 0;
        __syncthreads();
        lbase[t] += x;
        __syncthreads();
    }
    int excl = lbase[t] - h;
    __syncthreads();
    lbase[t] = excl;
    lcur[t] = 0;
    if (t < NB) gbase[t] = h ? atomicAdd(&cursor[t * CSTRIDE], h) : 0;
    __syncthreads();
    for (int j = t; j < cnt; j += 256) {        // stage bucket-sorted
        int d = dst[e0 + j];
        int b = d >> 9;
        int pos = lbase[b] + atomicAdd(&lcur[b], 1);
        stage[pos] = ((d & 511) << 17) | src[e0 + j];
        sbkt[pos] = (unsigned char)b;
    }
    __syncthreads();
    for (int j = t; j < cnt; j += 256) {        // contiguous-run copy out
        int b = sbkt[j];
        int gpos = gbase[b] + (j - lbase[b]);
        if (gpos < CAP) bkt[b * CAP + gpos] = stage[j];
    }
}

// One workgroup per bucket: scan all bucket counts for global base, LDS
// histogram of 512 local nodes, LDS scan, write row_ptr/dinv, place csr_src.
__global__ void k_bfine(const int* __restrict__ cursor, const int* __restrict__ bkt,
                        int* __restrict__ row_ptr, float* __restrict__ dinv,
                        int* __restrict__ csr_src) {
    __shared__ int sd[256];
    __shared__ int cnt[512];
    __shared__ int excl[512];
    __shared__ int s2[256];
    int b = blockIdx.x;
    int t = threadIdx.x;
    int c = (t < NB) ? cursor[t * CSTRIDE] : 0;
    sd[t] = c;
    __syncthreads();
    for (int off = 1; off < 256; off <<= 1) {
        int x = (t >= off) ? sd[t - off] : 0;
        __syncthreads();
        sd[t] += x;
        __syncthreads();
    }
    int m = cursor[b * CSTRIDE];
    int base = sd[b] - m;                       // exclusive prefix of bucket b
    if (b == 0 && t == 0) row_ptr[N] = E;
    const int* bb = bkt + b * CAP;
    cnt[t] = 0; cnt[t + 256] = 0;
    __syncthreads();
    for (int j = t; j < m; j += 256) atomicAdd(&cnt[bb[j] >> 17], 1);
    __syncthreads();
    int pairSum = cnt[2 * t] + cnt[2 * t + 1];
    s2[t] = pairSum;
    __syncthreads();
    for (int off = 1; off < 256; off <<= 1) {
        int x = (t >= off) ? s2[t - off] : 0;
        __syncthreads();
        s2[t] += x;
        __syncthreads();
    }
    int exclPair = s2[t] - pairSum;
    excl[2 * t] = exclPair;
    excl[2 * t + 1] = exclPair + cnt[2 * t];
    __syncthreads();
#pragma unroll
    for (int hh = 0; hh < 2; ++hh) {
        int k = t + hh * 256;
        int node = b * 512 + k;
        if (node < N) {
            row_ptr[node] = base + excl[k];
            dinv[node] = rsqrtf((float)(cnt[k] + 1));
        }
    }
    __syncthreads();
    for (int j = t; j < m; j += 256) {
        int v = bb[j];
        int p = atomicAdd(&excl[v >> 17], 1);   // excl doubles as cursor
        csr_src[base + p] = v & 0x1FFFF;
    }
}

// h1s[row][c] = (X[row] . W1[:,c]) * dinv[row], stored bf16 (packed stores).
// Also zeroes dummy rows h1s[N] / h2s[N] (gather padding targets).
__global__ void k_gemm1(const float* __restrict__ X, const float* __restrict__ W1,
                        const float* __restrict__ dinv, __hip_bfloat16* __restrict__ h1s,
                        __hip_bfloat16* __restrict__ h2s) {
    int t = threadIdx.x;
    int lane = t & 63;
    int wid = (blockIdx.x * 256 + t) >> 6;  // 4096 waves
    if (blockIdx.x == 0) {
        if (t < 64) h1s[(size_t)N * 64 + t] = __float2bfloat16(0.f);
        if (t < 16) h2s[(size_t)N * 16 + t] = __float2bfloat16(0.f);
    }
    float w1[64];
#pragma unroll
    for (int k = 0; k < 64; ++k) w1[k] = W1[k * 64 + lane];
    for (int row = wid; row < N; row += 4096) {
        float x = X[(size_t)row * 64 + lane];
        float acc = 0.f;
#pragma unroll
        for (int k = 0; k < 64; ++k) acc = fmaf(rl_f(x, k), w1[k], acc);
        acc *= dinv[row];
        float up = __shfl_xor(acc, 1);
        if (!(lane & 1)) {
            __hip_bfloat162 p;
            p.x = __float2bfloat16(acc);
            p.y = __float2bfloat16(up);
            *(__hip_bfloat162*)(h1s + (size_t)row * 64 + lane) = p;
        }
    }
}

// Fused: gather layer-1 (CSR), +b1, relu, y1@W2, scale -> h2s (bf16).
// Wave handles NPW contiguous nodes. 8 edges per uint4 load; src indices
// broadcast via __shfl under wave-uniform bounds; padded lanes carry the
// dummy zero row N (no predication).
__global__ void k_layer12(const int* __restrict__ row_ptr, const int* __restrict__ csr_src,
                          const float* __restrict__ dinv, const __hip_bfloat16* __restrict__ h1s,
                          const float* __restrict__ b1, const float* __restrict__ W2,
                          __hip_bfloat16* __restrict__ h2s) {
    __shared__ float sy[4][8][72];              // stride-72 pad: conflict-free
    int t = threadIdx.x;
    int lane = t & 63;
    int w = t >> 6;
    int g8 = lane >> 3;                         // edge slot within step
    int qo = (lane & 7) << 4;                   // byte offset of 16B feat slice
    int g16 = lane >> 4, c16 = lane & 15;       // W2-stage layout
    int wid = blockIdx.x * 4 + w;
    int d0 = wid * NPW;
    if (d0 >= N) return;
    int dend = min(d0 + NPW, N);
    float w2[16];
#pragma unroll
    for (int j = 0; j < 16; ++j) w2[j] = W2[(g16 * 16 + j) * 16 + c16];
    float b1v = b1[lane];
    const char* Hb = (const char*)h1s;

    int rp0 = row_ptr[d0];
    for (int d = d0; d < dend; ++d) {
        int rp1 = row_ptr[d + 1];
        float dv = dinv[d];
        float a[8] = {0, 0, 0, 0, 0, 0, 0, 0};
        if (g8 == 0) {                          // self term (one 8-lane load)
            uint4 u = *(const uint4*)(Hb + (((unsigned)d << 7) | qo));
            a[0] = bflo(u.x); a[1] = bfhi(u.x); a[2] = bflo(u.y); a[3] = bfhi(u.y);
            a[4] = bflo(u.z); a[5] = bfhi(u.z); a[6] = bflo(u.w); a[7] = bfhi(u.w);
        }
        for (int base = rp0; base < rp1; base += 64) {   // wave-uniform bounds
            int nloc = min(64, rp1 - base);
            int sidx = (lane < nloc) ? csr_src[base + lane] : N;   // pad -> zero row
            int steps = (nloc + 7) >> 3;
            for (int j = 0; j < steps; ++j) {            // uniform trip count
                int s = __shfl(sidx, (j << 3) | g8);     // 1 bpermute
                uint4 u = *(const uint4*)(Hb + (((unsigned)s << 7) | qo));
                a[0] += bflo(u.x); a[1] += bfhi(u.x);
                a[2] += bflo(u.y); a[3] += bfhi(u.y);
                a[4] += bflo(u.z); a[5] += bfhi(u.z);
                a[6] += bflo(u.w); a[7] += bfhi(u.w);
            }
        }
        rp0 = rp1;
        // LDS transpose: partials (8 groups x 64 feats) -> y[feat=lane]
        float* row = &sy[w][g8][(lane & 7) << 3];
        *(float4*)row = make_float4(a[0], a[1], a[2], a[3]);
        *(float4*)(row + 4) = make_float4(a[4], a[5], a[6], a[7]);
        __builtin_amdgcn_s_waitcnt(0);          // lgkmcnt(0): within-wave LDS order
        float ysum = sy[w][0][lane] + sy[w][1][lane] + sy[w][2][lane] + sy[w][3][lane]
                   + sy[w][4][lane] + sy[w][5][lane] + sy[w][6][lane] + sy[w][7][lane];
        float y = fmaxf(fmaf(dv, ysum, b1v), 0.f);
        // h2[c] = sum_k y[k]*W2[k][c]; group g16 covers k = g16*16..+15
        float o = 0.f;
#pragma unroll
        for (int j = 0; j < 16; ++j) o = fmaf(__shfl(y, (lane & 48) | j), w2[j], o);
        o += __shfl_xor(o, 16);
        o += __shfl_xor(o, 32);
        o *= dv;
        float oup = __shfl_xor(o, 1);
        if (lane < 16 && !(lane & 1)) {
            __hip_bfloat162 p;
            p.x = __float2bfloat16(o);
            p.y = __float2bfloat16(oup);
            *(__hip_bfloat162*)(h2s + (size_t)d * 16 + lane) = p;
        }
    }
}

// out[d] = dinv[d]*(h2s[d] + sum_in h2s[s]) + b2.  16 edges per step (uint2,
// 4 lanes/edge), dummy-row padding, float4 stores.
__global__ void k_gather2(const int* __restrict__ row_ptr, const int* __restrict__ csr_src,
                          const float* __restrict__ dinv, const __hip_bfloat16* __restrict__ h2s,
                          const float* __restrict__ b2, float* __restrict__ out) {
    int t = threadIdx.x;
    int lane = t & 63;
    int g4 = lane >> 2;                         // edge slot within step
    int q2 = lane & 3;                          // 8B feat slice
    int qo = q2 << 3;
    int wid = blockIdx.x * 4 + (t >> 6);
    int d0 = wid * NPW;
    if (d0 >= N) return;
    int dend = min(d0 + NPW, N);
    float b2v[4];
#pragma unroll
    for (int k = 0; k < 4; ++k) b2v[k] = b2[q2 * 4 + k];
    const char* Hb = (const char*)h2s;

    int rp0 = row_ptr[d0];
    for (int d = d0; d < dend; ++d) {
        int rp1 = row_ptr[d + 1];
        float dv = dinv[d];
        float a[4] = {0, 0, 0, 0};
        if (g4 == 0) {                          // self term
            uint2 u = *(const uint2*)(Hb + (((unsigned)d << 5) | qo));
            a[0] = bflo(u.x); a[1] = bfhi(u.x); a[2] = bflo(u.y); a[3] = bfhi(u.y);
        }
        for (int base = rp0; base < rp1; base += 64) {
            int nloc = min(64, rp1 - base);
            int sidx = (lane < nloc) ? csr_src[base + lane] : N;
            int steps = (nloc + 15) >> 4;
            for (int j = 0; j < steps; ++j) {
                int s = __shfl(sidx, (j << 4) | g4);
                uint2 u = *(const uint2*)(Hb + (((unsigned)s << 5) | qo));
                a[0] += bflo(u.x); a[1] += bfhi(u.x);
                a[2] += bflo(u.y); a[3] += bfhi(u.y);
            }
        }
        rp0 = rp1;
#pragma unroll
        for (int k = 0; k < 4; ++k) {
            a[k] += __shfl_xor(a[k], 4);
            a[k] += __shfl_xor(a[k], 8);
            a[k] += __shfl_xor(a[k], 16);
            a[k] += __shfl_xor(a[k], 32);
        }
        if (lane < 4) {
            float4 r;
            r.x = fmaf(dv, a[0], b2v[0]);
            r.y = fmaf(dv, a[1], b2v[1]);
            r.z = fmaf(dv, a[2], b2v[2]);
            r.w = fmaf(dv, a[3], b2v[3]);
            *(float4*)(out + (size_t)d * 16 + q2 * 4) = r;
        }
    }
}

extern "C" void kernel_launch(void* const* d_in, const int* in_sizes, int n_in,
                              void* d_out, int out_size, void* d_ws, size_t ws_size,
                              hipStream_t stream) {
    const float* X  = (const float*)d_in[0];
    const int*   ei = (const int*)d_in[1];  // [2, E] int32: src then dst
    const float* W1 = (const float*)d_in[2];
    const float* b1 = (const float*)d_in[3];
    const float* W2 = (const float*)d_in[4];
    const float* b2 = (const float*)d_in[5];
    float* out = (float*)d_out;

    int* cursor  = (int*)d_ws;                     // NB*CSTRIDE = 6272
    int* row_ptr = cursor + NB * CSTRIDE;          // N+4 (pad keeps h1s 16B-aligned)
    int* bkt     = row_ptr + N + 4;                // NB*CAP
    int* csr_src = bkt + NB * CAP;                 // E
    float* dinv  = (float*)(csr_src + E);          // N
    __hip_bfloat16* h1s = (__hip_bfloat16*)(dinv + N);  // (N+1)*64, 16B-aligned
    __hip_bfloat16* h2s = h1s + (size_t)(N + 1) * 64;   // (N+1)*16, 16B-aligned

    const int* src = ei;
    const int* dst = ei + E;

    hipMemsetAsync(cursor, 0, NB * CSTRIDE * sizeof(int), stream);
    k_bfill<<<NBLK, 256, 0, stream>>>(src, dst, cursor, bkt);
    k_bfine<<<NB, 256, 0, stream>>>(cursor, bkt, row_ptr, dinv, csr_src);
    k_gemm1<<<1024, 256, 0, stream>>>(X, W1, dinv, h1s, h2s);
    k_layer12<<<NWBLK, 256, 0, stream>>>(row_ptr, csr_src, dinv, h1s, b1, W2, h2s);
    k_gather2<<<NWBLK, 256, 0, stream>>>(row_ptr, csr_src, dinv, h2s, b2, out);
}